// Round 3
// baseline (1167.218 us; speedup 1.0000x reference)
//
#include <hip/hip_runtime.h>
#include <math.h>

// ---------------- degree / normalization ----------------

__global__ void deg_init_kernel(int* __restrict__ deg, int n) {
    int i = blockIdx.x * blockDim.x + threadIdx.x;
    if (i < n) deg[i] = 1;  // self loop
}

__global__ void deg_count_kernel(const int* __restrict__ dst, int E, int* __restrict__ deg) {
    int i = blockIdx.x * blockDim.x + threadIdx.x;
    if (i < E) atomicAdd(&deg[dst[i]], 1);
}

__global__ void dis_kernel(const int* __restrict__ deg, float* __restrict__ dis, int n) {
    int i = blockIdx.x * blockDim.x + threadIdx.x;
    if (i < n) dis[i] = rsqrtf((float)deg[i]);
}

// ---------------- fp32 row-tiled GEMM ----------------
// C[M,N] = op_in(A[M,K]) @ W[K,N] (+bias) (relu_out)
// blockDim.x == N (threads = output columns), TM rows per block.

template<int TM, bool RELU_IN, bool RELU_OUT, bool BIAS>
__global__ void gemm_kernel(const float* __restrict__ A, const float* __restrict__ W,
                            const float* __restrict__ bias, float* __restrict__ C,
                            int M, int K, int N) {
    extern __shared__ float As[];  // TM*K floats
    const int row0 = blockIdx.x * TM;
    const int col  = threadIdx.x;

    const int total = TM * K;
    for (int idx = threadIdx.x; idx < total; idx += blockDim.x) {
        int r = idx / K;
        int k = idx - r * K;
        int gr = row0 + r;
        float v = (gr < M) ? A[(size_t)gr * K + k] : 0.0f;
        if (RELU_IN) v = fmaxf(v, 0.0f);
        As[idx] = v;
    }
    __syncthreads();

    float acc[TM];
#pragma unroll
    for (int r = 0; r < TM; ++r) acc[r] = 0.0f;

    for (int k = 0; k < K; ++k) {
        float wv = W[(size_t)k * N + col];
#pragma unroll
        for (int r = 0; r < TM; ++r) acc[r] += As[r * K + k] * wv;
    }

    float b = BIAS ? bias[col] : 0.0f;
#pragma unroll
    for (int r = 0; r < TM; ++r) {
        int gr = row0 + r;
        if (gr < M) {
            float v = acc[r] + b;
            if (RELU_OUT) v = fmaxf(v, 0.0f);
            C[(size_t)gr * N + col] = v;
        }
    }
}

// ---------------- self-loop init: out = dis[i]^2 * XW + bias ----------------

template<int C>
__global__ void self_init_kernel(const float* __restrict__ XW, const float* __restrict__ dis,
                                 const float* __restrict__ bias, float* __restrict__ out,
                                 int n) {
    int i = blockIdx.x * blockDim.x + threadIdx.x;
    int total = n * C;
    if (i < total) {
        int r = i / C;
        int c = i - r * C;
        float di = dis[r];
        out[i] = XW[i] * di * di + bias[c];
    }
}

// ---------------- edge scatter (atomic) ----------------
// 128-wide: one wave per edge, each lane does 2 columns via float2 gather.

__global__ void scatter128_kernel(const float* __restrict__ XW, const int* __restrict__ src,
                                  const int* __restrict__ dst, const float* __restrict__ dis,
                                  float* __restrict__ out, int E) {
    int gtid = blockIdx.x * blockDim.x + threadIdx.x;
    int wave = gtid >> 6;
    int lane = threadIdx.x & 63;
    int nwaves = (gridDim.x * blockDim.x) >> 6;
    for (int e = wave; e < E; e += nwaves) {
        int s = src[e], d = dst[e];
        float norm = dis[s] * dis[d];
        float2 v = ((const float2*)(XW + (size_t)s * 128))[lane];
        float* orow = out + (size_t)d * 128;
        atomicAdd(&orow[lane * 2 + 0], v.x * norm);
        atomicAdd(&orow[lane * 2 + 1], v.y * norm);
    }
}

// 64-wide: one wave per edge, one column per lane.
__global__ void scatter64_kernel(const float* __restrict__ XW, const int* __restrict__ src,
                                 const int* __restrict__ dst, const float* __restrict__ dis,
                                 float* __restrict__ out, int E) {
    int gtid = blockIdx.x * blockDim.x + threadIdx.x;
    int wave = gtid >> 6;
    int lane = threadIdx.x & 63;
    int nwaves = (gridDim.x * blockDim.x) >> 6;
    for (int e = wave; e < E; e += nwaves) {
        int s = src[e], d = dst[e];
        float norm = dis[s] * dis[d];
        float v = XW[(size_t)s * 64 + lane];
        atomicAdd(&out[(size_t)d * 64 + lane], v * norm);
    }
}

// ---------------- launch ----------------

extern "C" void kernel_launch(void* const* d_in, const int* in_sizes, int n_in,
                              void* d_out, int out_size, void* d_ws, size_t ws_size,
                              hipStream_t stream) {
    const float* x     = (const float*)d_in[0];  // [n,180]
    const float* fc1_w = (const float*)d_in[1];  // [180,128]
    const float* fc1_b = (const float*)d_in[2];  // [128]
    const float* w1    = (const float*)d_in[3];  // [128,128]
    const float* b1    = (const float*)d_in[4];  // [128]
    const float* w2    = (const float*)d_in[5];  // [128,64]
    const float* b2    = (const float*)d_in[6];  // [64]
    const int*   edges = (const int*)d_in[7];    // [2,E] int32

    const int IN_DIM = 180, HID = 128, OUT_DIM = 64;
    const int n = in_sizes[0] / IN_DIM;          // 50000
    const int E = in_sizes[7] / 2;               // 800000
    const int* src = edges;
    const int* dst = edges + E;

    float* out = (float*)d_out;                  // [n,64]

    // workspace layout (aligned to 256B)
    char* ws = (char*)d_ws;
    auto align = [](size_t v) { return (v + 255) & ~(size_t)255; };
    int*   deg  = (int*)ws;
    size_t off  = align((size_t)n * sizeof(int));
    float* dis  = (float*)(ws + off);
    off += align((size_t)n * sizeof(float));
    float* bufA = (float*)(ws + off);            // n*128 floats (H1, then conv1 accum)
    off += align((size_t)n * HID * sizeof(float));
    float* bufB = (float*)(ws + off);            // n*128 floats (XW1, then XW2)

    const int TM = 16;

    // degree + normalization
    deg_init_kernel<<<(n + 255) / 256, 256, 0, stream>>>(deg, n);
    deg_count_kernel<<<(E + 255) / 256, 256, 0, stream>>>(dst, E, deg);
    dis_kernel<<<(n + 255) / 256, 256, 0, stream>>>(deg, dis, n);

    // H1 = relu(x @ fc1_w + fc1_b)   [n,128]  -> bufA
    gemm_kernel<TM, false, true, true>
        <<<(n + TM - 1) / TM, HID, TM * IN_DIM * sizeof(float), stream>>>(
            x, fc1_w, fc1_b, bufA, n, IN_DIM, HID);

    // XW1 = H1 @ w1                  [n,128]  -> bufB
    gemm_kernel<TM, false, false, false>
        <<<(n + TM - 1) / TM, HID, TM * HID * sizeof(float), stream>>>(
            bufA, w1, nullptr, bufB, n, HID, HID);

    // conv1 accum: bufA = dis^2 * XW1 + b1, then scatter edges
    self_init_kernel<128><<<((size_t)n * HID + 255) / 256, 256, 0, stream>>>(
        bufB, dis, b1, bufA, n);
    scatter128_kernel<<<8192, 256, 0, stream>>>(bufB, src, dst, dis, bufA, E);

    // XW2 = relu(bufA) @ w2          [n,64]   -> bufB
    gemm_kernel<TM, true, false, false>
        <<<(n + TM - 1) / TM, OUT_DIM, TM * HID * sizeof(float), stream>>>(
            bufA, w2, nullptr, bufB, n, HID, OUT_DIM);

    // conv2 accum: out = dis^2 * XW2 + b2, then scatter edges
    self_init_kernel<64><<<((size_t)n * OUT_DIM + 255) / 256, 256, 0, stream>>>(
        bufB, dis, b2, out, n);
    scatter64_kernel<<<8192, 256, 0, stream>>>(bufB, src, dst, dis, out, E);
}

// Round 5
// 601.749 us; speedup vs baseline: 1.9397x; 1.9397x over previous
//
#include <hip/hip_runtime.h>
#include <math.h>

// ================= degree / normalization =================

__global__ void deg_init_kernel(int* __restrict__ deg, int n) {
    int i = blockIdx.x * blockDim.x + threadIdx.x;
    if (i < n) deg[i] = 1;  // self loop
}

__global__ void deg_count_kernel(const int* __restrict__ dst, int E, int* __restrict__ deg) {
    int i = blockIdx.x * blockDim.x + threadIdx.x;
    if (i < E) atomicAdd(&deg[dst[i]], 1);
}

__global__ void dis_kernel(const int* __restrict__ deg, float* __restrict__ dis, int n) {
    int i = blockIdx.x * blockDim.x + threadIdx.x;
    if (i < n) dis[i] = rsqrtf((float)deg[i]);
}

// ================= CSR build =================
// Single-block chunked exclusive scan of indeg (= deg-1) -> row_start[0..n], cursor copy.

__global__ void scan_kernel(const int* __restrict__ deg, int* __restrict__ row_start,
                            int* __restrict__ cursor, int n) {
    __shared__ int sm[1024];
    __shared__ int carry;
    const int tid = threadIdx.x;
    if (tid == 0) carry = 0;
    __syncthreads();
    for (int base = 0; base < n; base += 1024) {
        int i = base + tid;
        int v = (i < n) ? (deg[i] - 1) : 0;
        sm[tid] = v;
        __syncthreads();
        for (int off = 1; off < 1024; off <<= 1) {
            int t = (tid >= off) ? sm[tid - off] : 0;
            __syncthreads();
            sm[tid] += t;
            __syncthreads();
        }
        if (i < n) {
            int excl = carry + sm[tid] - v;
            row_start[i] = excl;
            cursor[i] = excl;
        }
        __syncthreads();
        if (tid == 0) carry += sm[1023];
        __syncthreads();
    }
    if (tid == 0) row_start[n] = carry;
}

__global__ void csr_fill_kernel(const int* __restrict__ src, const int* __restrict__ dst,
                                int E, int* __restrict__ cursor, int* __restrict__ csr) {
    int e = blockIdx.x * blockDim.x + threadIdx.x;
    if (e < E) {
        int pos = atomicAdd(&cursor[dst[e]], 1);
        csr[pos] = src[e];
    }
}

// ================= fp32 row-tiled GEMM =================
// C[M,N] = op_in(A[M,K]) @ W[K,N] (+bias) (relu_out) (optionally * dis[row])
// blockDim.x == N, TM rows per block. K % 4 == 0 required.

template<int TM, bool RELU_IN, bool RELU_OUT, bool BIAS, bool DIS_SCALE>
__global__ void gemm_kernel(const float* __restrict__ A, const float* __restrict__ W,
                            const float* __restrict__ bias, const float* __restrict__ dis,
                            float* __restrict__ C, int M, int K, int N) {
    extern __shared__ float As[];  // TM*K floats
    const int row0 = blockIdx.x * TM;
    const int col  = threadIdx.x;

    const int total = TM * K;
    for (int idx = threadIdx.x; idx < total; idx += blockDim.x) {
        int r = idx / K;
        int k = idx - r * K;
        int gr = row0 + r;
        float v = (gr < M) ? A[(size_t)gr * K + k] : 0.0f;
        if (RELU_IN) v = fmaxf(v, 0.0f);
        As[idx] = v;
    }
    __syncthreads();

    float acc[TM];
#pragma unroll
    for (int r = 0; r < TM; ++r) acc[r] = 0.0f;

    for (int k = 0; k < K; k += 4) {
        float w0 = W[(size_t)(k + 0) * N + col];
        float w1 = W[(size_t)(k + 1) * N + col];
        float w2 = W[(size_t)(k + 2) * N + col];
        float w3 = W[(size_t)(k + 3) * N + col];
#pragma unroll
        for (int r = 0; r < TM; ++r) {
            float4 a = *(const float4*)&As[r * K + k];
            acc[r] += a.x * w0 + a.y * w1 + a.z * w2 + a.w * w3;
        }
    }

    float b = BIAS ? bias[col] : 0.0f;
#pragma unroll
    for (int r = 0; r < TM; ++r) {
        int gr = row0 + r;
        if (gr < M) {
            float v = acc[r];
            if (DIS_SCALE) v *= dis[gr];
            v += b;
            if (RELU_OUT) v = fmaxf(v, 0.0f);
            C[(size_t)gr * N + col] = v;
        }
    }
}

// ================= CSR gather aggregation =================
// out[d] = (maybe relu)( dis[d] * (y[d] + sum_{s in N(d)} y[s]) + bias )
// One wave per dst node.

template<bool RELU>
__global__ void gather128_kernel(const float* __restrict__ y, const int* __restrict__ row_start,
                                 const int* __restrict__ csr, const float* __restrict__ dis,
                                 const float* __restrict__ bias, float* __restrict__ out, int n) {
    int w = (blockIdx.x * blockDim.x + threadIdx.x) >> 6;
    if (w >= n) return;
    int lane = threadIdx.x & 63;

    float2 acc = ((const float2*)(y + (size_t)w * 128))[lane];  // self loop
    int p  = row_start[w];
    int pe = row_start[w + 1];
    for (; p + 1 < pe; p += 2) {
        int s0 = __builtin_amdgcn_readfirstlane(csr[p]);
        int s1 = __builtin_amdgcn_readfirstlane(csr[p + 1]);
        float2 v0 = ((const float2*)(y + (size_t)s0 * 128))[lane];
        float2 v1 = ((const float2*)(y + (size_t)s1 * 128))[lane];
        acc.x += v0.x + v1.x;
        acc.y += v0.y + v1.y;
    }
    if (p < pe) {
        int s0 = __builtin_amdgcn_readfirstlane(csr[p]);
        float2 v0 = ((const float2*)(y + (size_t)s0 * 128))[lane];
        acc.x += v0.x;
        acc.y += v0.y;
    }
    float dd = dis[w];
    float2 b = ((const float2*)bias)[lane];
    float ox = acc.x * dd + b.x;
    float oy = acc.y * dd + b.y;
    if (RELU) { ox = fmaxf(ox, 0.0f); oy = fmaxf(oy, 0.0f); }
    ((float2*)(out + (size_t)w * 128))[lane] = make_float2(ox, oy);
}

template<bool RELU>
__global__ void gather64_kernel(const float* __restrict__ y, const int* __restrict__ row_start,
                                const int* __restrict__ csr, const float* __restrict__ dis,
                                const float* __restrict__ bias, float* __restrict__ out, int n) {
    int w = (blockIdx.x * blockDim.x + threadIdx.x) >> 6;
    if (w >= n) return;
    int lane = threadIdx.x & 63;

    float acc = y[(size_t)w * 64 + lane];  // self loop
    int p  = row_start[w];
    int pe = row_start[w + 1];
    for (; p + 1 < pe; p += 2) {
        int s0 = __builtin_amdgcn_readfirstlane(csr[p]);
        int s1 = __builtin_amdgcn_readfirstlane(csr[p + 1]);
        float v0 = y[(size_t)s0 * 64 + lane];
        float v1 = y[(size_t)s1 * 64 + lane];
        acc += v0 + v1;
    }
    if (p < pe) {
        int s0 = __builtin_amdgcn_readfirstlane(csr[p]);
        acc += y[(size_t)s0 * 64 + lane];
    }
    float v = acc * dis[w] + bias[lane];
    if (RELU) v = fmaxf(v, 0.0f);
    out[(size_t)w * 64 + lane] = v;
}

// ================= fallback atomic scatter path (proven round-0) =================

template<int C>
__global__ void self_init_kernel(const float* __restrict__ XW, const float* __restrict__ dis,
                                 const float* __restrict__ bias, float* __restrict__ out,
                                 int n) {
    int i = blockIdx.x * blockDim.x + threadIdx.x;
    int total = n * C;
    if (i < total) {
        int r = i / C;
        int c = i - r * C;
        float di = dis[r];
        out[i] = XW[i] * di * di + bias[c];
    }
}

__global__ void scatter128_kernel(const float* __restrict__ XW, const int* __restrict__ src,
                                  const int* __restrict__ dst, const float* __restrict__ dis,
                                  float* __restrict__ out, int E) {
    int gtid = blockIdx.x * blockDim.x + threadIdx.x;
    int wave = gtid >> 6;
    int lane = threadIdx.x & 63;
    int nwaves = (gridDim.x * blockDim.x) >> 6;
    for (int e = wave; e < E; e += nwaves) {
        int s = src[e], d = dst[e];
        float norm = dis[s] * dis[d];
        float2 v = ((const float2*)(XW + (size_t)s * 128))[lane];
        float* orow = out + (size_t)d * 128;
        atomicAdd(&orow[lane * 2 + 0], v.x * norm);
        atomicAdd(&orow[lane * 2 + 1], v.y * norm);
    }
}

__global__ void scatter64_kernel(const float* __restrict__ XW, const int* __restrict__ src,
                                 const int* __restrict__ dst, const float* __restrict__ dis,
                                 float* __restrict__ out, int E) {
    int gtid = blockIdx.x * blockDim.x + threadIdx.x;
    int wave = gtid >> 6;
    int lane = threadIdx.x & 63;
    int nwaves = (gridDim.x * blockDim.x) >> 6;
    for (int e = wave; e < E; e += nwaves) {
        int s = src[e], d = dst[e];
        float norm = dis[s] * dis[d];
        float v = XW[(size_t)s * 64 + lane];
        atomicAdd(&out[(size_t)d * 64 + lane], v * norm);
    }
}

// ================= launch =================

extern "C" void kernel_launch(void* const* d_in, const int* in_sizes, int n_in,
                              void* d_out, int out_size, void* d_ws, size_t ws_size,
                              hipStream_t stream) {
    const float* x     = (const float*)d_in[0];  // [n,180]
    const float* fc1_w = (const float*)d_in[1];  // [180,128]
    const float* fc1_b = (const float*)d_in[2];  // [128]
    const float* w1    = (const float*)d_in[3];  // [128,128]
    const float* b1    = (const float*)d_in[4];  // [128]
    const float* w2    = (const float*)d_in[5];  // [128,64]
    const float* b2    = (const float*)d_in[6];  // [64]
    const int*   edges = (const int*)d_in[7];    // [2,E] int32

    const int IN_DIM = 180, HID = 128, OUT_DIM = 64;
    const int n = in_sizes[0] / IN_DIM;          // 50000
    const int E = in_sizes[7] / 2;               // 800000
    const int* src = edges;
    const int* dst = edges + E;

    float* out = (float*)d_out;                  // [n,64]

    char* ws = (char*)d_ws;
    auto align = [](size_t v) { return (v + 255) & ~(size_t)255; };

    size_t off = 0;
    int*   deg       = (int*)(ws + off);  off += align((size_t)n * sizeof(int));
    float* dis       = (float*)(ws + off); off += align((size_t)n * sizeof(float));
    int*   row_start = (int*)(ws + off);  off += align((size_t)(n + 1) * sizeof(int));
    int*   cursor    = (int*)(ws + off);  off += align((size_t)n * sizeof(int));
    int*   csr       = (int*)(ws + off);  off += align((size_t)E * sizeof(int));
    float* bufA      = (float*)(ws + off); off += align((size_t)n * HID * sizeof(float));
    float* bufB      = (float*)(ws + off); off += align((size_t)n * HID * sizeof(float));
    const bool use_csr = (off <= ws_size);

    const int TM = 16;
    const int nblk256 = (n + 255) / 256;
    const int eblk256 = (E + 255) / 256;
    const int gemm_grid = (n + TM - 1) / TM;

    // degree + normalization (shared by both paths)
    deg_init_kernel<<<nblk256, 256, 0, stream>>>(deg, n);
    deg_count_kernel<<<eblk256, 256, 0, stream>>>(dst, E, deg);
    dis_kernel<<<nblk256, 256, 0, stream>>>(deg, dis, n);

    if (use_csr) {
        // CSR build
        scan_kernel<<<1, 1024, 0, stream>>>(deg, row_start, cursor, n);
        csr_fill_kernel<<<eblk256, 256, 0, stream>>>(src, dst, E, cursor, csr);

        // H1 = relu(x @ fc1_w + fc1_b) -> bufA
        gemm_kernel<TM, false, true, true, false>
            <<<gemm_grid, HID, TM * IN_DIM * sizeof(float), stream>>>(
                x, fc1_w, fc1_b, nullptr, bufA, n, IN_DIM, HID);

        // y1 = dis * (H1 @ w1) -> bufB
        gemm_kernel<TM, false, false, false, true>
            <<<gemm_grid, HID, TM * HID * sizeof(float), stream>>>(
                bufA, w1, nullptr, dis, bufB, n, HID, HID);

        // H2 = relu(dis[d]*(y1[d] + sum y1[s]) + b1) -> bufA
        gather128_kernel<true><<<(n + 3) / 4, 256, 0, stream>>>(
            bufB, row_start, csr, dis, b1, bufA, n);

        // y2 = dis * (H2 @ w2) -> bufB
        gemm_kernel<TM, false, false, false, true>
            <<<gemm_grid, OUT_DIM, TM * HID * sizeof(float), stream>>>(
                bufA, w2, nullptr, dis, bufB, n, HID, OUT_DIM);

        // out = dis[d]*(y2[d] + sum y2[s]) + b2
        gather64_kernel<false><<<(n + 3) / 4, 256, 0, stream>>>(
            bufB, row_start, csr, dis, b2, out, n);
    } else {
        // fallback: round-0 atomic scatter path (uses only deg/dis/bufA/bufB)
        size_t o2 = 0;
        int*   deg2  = (int*)(ws + o2);   o2 += align((size_t)n * sizeof(int));
        float* dis2  = (float*)(ws + o2); o2 += align((size_t)n * sizeof(float));
        float* bA    = (float*)(ws + o2); o2 += align((size_t)n * HID * sizeof(float));
        float* bB    = (float*)(ws + o2);
        (void)deg2; (void)dis2;

        gemm_kernel<TM, false, true, true, false>
            <<<gemm_grid, HID, TM * IN_DIM * sizeof(float), stream>>>(
                x, fc1_w, fc1_b, nullptr, bA, n, IN_DIM, HID);
        gemm_kernel<TM, false, false, false, false>
            <<<gemm_grid, HID, TM * HID * sizeof(float), stream>>>(
                bA, w1, nullptr, nullptr, bB, n, HID, HID);
        self_init_kernel<128><<<((size_t)n * HID + 255) / 256, 256, 0, stream>>>(
            bB, dis, b1, bA, n);
        scatter128_kernel<<<8192, 256, 0, stream>>>(bB, src, dst, dis, bA, E);
        gemm_kernel<TM, true, false, false, false>
            <<<gemm_grid, OUT_DIM, TM * HID * sizeof(float), stream>>>(
                bA, w2, nullptr, nullptr, bB, n, HID, OUT_DIM);
        self_init_kernel<64><<<((size_t)n * OUT_DIM + 255) / 256, 256, 0, stream>>>(
            bB, dis, b2, out, n);
        scatter64_kernel<<<8192, 256, 0, stream>>>(bB, src, dst, dis, out, E);
    }
}

// Round 7
// 537.971 us; speedup vs baseline: 2.1697x; 1.1186x over previous
//
#include <hip/hip_runtime.h>
#include <math.h>

// ================= degree / normalization =================

__global__ void deg_init_kernel(int* __restrict__ deg, int n) {
    int i = blockIdx.x * blockDim.x + threadIdx.x;
    if (i < n) deg[i] = 1;  // self loop
}

__global__ void deg_count_kernel(const int* __restrict__ dst, int E, int* __restrict__ deg) {
    int i = blockIdx.x * blockDim.x + threadIdx.x;
    if (i < E) atomicAdd(&deg[dst[i]], 1);
}

__global__ void dis_kernel(const int* __restrict__ deg, float* __restrict__ dis, int n) {
    int i = blockIdx.x * blockDim.x + threadIdx.x;
    if (i < n) dis[i] = rsqrtf((float)deg[i]);
}

// ================= CSR build =================
// Single-block chunked exclusive scan of indeg (= deg-1) -> row_start[0..n], cursor copy.
// (proven correct round 5; revisit only if counters show it matters)

__global__ void scan_kernel(const int* __restrict__ deg, int* __restrict__ row_start,
                            int* __restrict__ cursor, int n) {
    __shared__ int sm[1024];
    __shared__ int carry;
    const int tid = threadIdx.x;
    if (tid == 0) carry = 0;
    __syncthreads();
    for (int base = 0; base < n; base += 1024) {
        int i = base + tid;
        int v = (i < n) ? (deg[i] - 1) : 0;
        sm[tid] = v;
        __syncthreads();
        for (int off = 1; off < 1024; off <<= 1) {
            int t = (tid >= off) ? sm[tid - off] : 0;
            __syncthreads();
            sm[tid] += t;
            __syncthreads();
        }
        if (i < n) {
            int excl = carry + sm[tid] - v;
            row_start[i] = excl;
            cursor[i] = excl;
        }
        __syncthreads();
        if (tid == 0) carry += sm[1023];
        __syncthreads();
    }
    if (tid == 0) row_start[n] = carry;
}

__global__ void csr_fill_kernel(const int* __restrict__ src, const int* __restrict__ dst,
                                int E, int* __restrict__ cursor, int* __restrict__ csr) {
    int e = blockIdx.x * blockDim.x + threadIdx.x;
    if (e < E) {
        int pos = atomicAdd(&cursor[dst[e]], 1);
        csr[pos] = src[e];
    }
}

// ================= fp32 GEMM, latency-tolerant =================
// C[M,NT] = op_in(A[M,KT]) @ W[KT,NT] (+bias) (relu_out) (optionally * dis[row])
// blockDim = NT*RG. Row-group rg = tid/NT handles TMG rows; block tile = TMG*RG rows.
// A tile staged in LDS (broadcast reads, conflict-free). W loads from L2 are
// software-pipelined via double-buffered float4 registers (named, no runtime idx).

template<int KT, int NT, int TMG, int RG, bool RELU_IN, bool RELU_OUT, bool BIAS, bool DIS_SCALE>
__global__ __launch_bounds__(NT* RG) void gemm_kernel(
    const float* __restrict__ A, const float* __restrict__ W,
    const float* __restrict__ bias, const float* __restrict__ dis,
    float* __restrict__ C, int M) {
    constexpr int TM = TMG * RG;
    extern __shared__ float As[];  // TM*KT floats
    const int row0 = blockIdx.x * TM;
    const int tid  = threadIdx.x;
    const int col  = tid & (NT - 1);
    const int rg   = tid / NT;

    // stage A tile (coalesced; zero-fill tail rows)
    constexpr int TOTAL = TM * KT;
    for (int idx = tid; idx < TOTAL; idx += NT * RG) {
        int r = idx / KT;
        int k = idx - r * KT;
        int gr = row0 + r;
        float v = (gr < M) ? A[(size_t)gr * KT + k] : 0.0f;
        if (RELU_IN) v = fmaxf(v, 0.0f);
        As[idx] = v;
    }
    __syncthreads();

    float acc[TMG];
#pragma unroll
    for (int r = 0; r < TMG; ++r) acc[r] = 0.0f;

    const float* Ab = As + rg * TMG * KT;
    const float* Wc = W + col;

    auto ldW = [&](int k) {
        return make_float4(Wc[(size_t)(k + 0) * NT], Wc[(size_t)(k + 1) * NT],
                           Wc[(size_t)(k + 2) * NT], Wc[(size_t)(k + 3) * NT]);
    };
    auto step = [&](int k, float4 w) {
#pragma unroll
        for (int r = 0; r < TMG; ++r) {
            float4 a = *(const float4*)(Ab + r * KT + k);
            acc[r] += a.x * w.x + a.y * w.y + a.z * w.z + a.w * w.w;
        }
    };

    // rotated 2-deep pipeline: prefetch next W chunk before current FMAs
    float4 wa = ldW(0), wb;
    int k = 0;
    while (true) {
        if (k + 4 < KT) wb = ldW(k + 4);
        step(k, wa);
        k += 4;
        if (k >= KT) break;
        if (k + 4 < KT) wa = ldW(k + 4);
        step(k, wb);
        k += 4;
        if (k >= KT) break;
    }

    float b = BIAS ? bias[col] : 0.0f;
#pragma unroll
    for (int r = 0; r < TMG; ++r) {
        int gr = row0 + rg * TMG + r;
        if (gr < M) {
            float v = acc[r];
            if (DIS_SCALE) v *= dis[gr];
            v += b;
            if (RELU_OUT) v = fmaxf(v, 0.0f);
            C[(size_t)gr * NT + col] = v;
        }
    }
}

// ================= CSR gather aggregation =================
// out[d] = (maybe relu)( dis[d] * (y[d] + sum_{s in N(d)} y[s]) + bias )
// One wave per dst node.

template<bool RELU>
__global__ void gather128_kernel(const float* __restrict__ y, const int* __restrict__ row_start,
                                 const int* __restrict__ csr, const float* __restrict__ dis,
                                 const float* __restrict__ bias, float* __restrict__ out, int n) {
    int w = (blockIdx.x * blockDim.x + threadIdx.x) >> 6;
    if (w >= n) return;
    int lane = threadIdx.x & 63;

    float2 acc = ((const float2*)(y + (size_t)w * 128))[lane];  // self loop
    int p  = row_start[w];
    int pe = row_start[w + 1];
    for (; p + 1 < pe; p += 2) {
        int s0 = __builtin_amdgcn_readfirstlane(csr[p]);
        int s1 = __builtin_amdgcn_readfirstlane(csr[p + 1]);
        float2 v0 = ((const float2*)(y + (size_t)s0 * 128))[lane];
        float2 v1 = ((const float2*)(y + (size_t)s1 * 128))[lane];
        acc.x += v0.x + v1.x;
        acc.y += v0.y + v1.y;
    }
    if (p < pe) {
        int s0 = __builtin_amdgcn_readfirstlane(csr[p]);
        float2 v0 = ((const float2*)(y + (size_t)s0 * 128))[lane];
        acc.x += v0.x;
        acc.y += v0.y;
    }
    float dd = dis[w];
    float2 b = ((const float2*)bias)[lane];
    float ox = acc.x * dd + b.x;
    float oy = acc.y * dd + b.y;
    if (RELU) { ox = fmaxf(ox, 0.0f); oy = fmaxf(oy, 0.0f); }
    ((float2*)(out + (size_t)w * 128))[lane] = make_float2(ox, oy);
}

template<bool RELU>
__global__ void gather64_kernel(const float* __restrict__ y, const int* __restrict__ row_start,
                                const int* __restrict__ csr, const float* __restrict__ dis,
                                const float* __restrict__ bias, float* __restrict__ out, int n) {
    int w = (blockIdx.x * blockDim.x + threadIdx.x) >> 6;
    if (w >= n) return;
    int lane = threadIdx.x & 63;

    float acc = y[(size_t)w * 64 + lane];  // self loop
    int p  = row_start[w];
    int pe = row_start[w + 1];
    for (; p + 1 < pe; p += 2) {
        int s0 = __builtin_amdgcn_readfirstlane(csr[p]);
        int s1 = __builtin_amdgcn_readfirstlane(csr[p + 1]);
        float v0 = y[(size_t)s0 * 64 + lane];
        float v1 = y[(size_t)s1 * 64 + lane];
        acc += v0 + v1;
    }
    if (p < pe) {
        int s0 = __builtin_amdgcn_readfirstlane(csr[p]);
        acc += y[(size_t)s0 * 64 + lane];
    }
    float v = acc * dis[w] + bias[lane];
    if (RELU) v = fmaxf(v, 0.0f);
    out[(size_t)w * 64 + lane] = v;
}

// ================= fallback atomic scatter path (proven round-3) =================

template<int C>
__global__ void self_init_kernel(const float* __restrict__ XW, const float* __restrict__ dis,
                                 const float* __restrict__ bias, float* __restrict__ out,
                                 int n) {
    int i = blockIdx.x * blockDim.x + threadIdx.x;
    int total = n * C;
    if (i < total) {
        int r = i / C;
        int c = i - r * C;
        float di = dis[r];
        out[i] = XW[i] * di * di + bias[c];
    }
}

__global__ void scatter128_kernel(const float* __restrict__ XW, const int* __restrict__ src,
                                  const int* __restrict__ dst, const float* __restrict__ dis,
                                  float* __restrict__ out, int E) {
    int gtid = blockIdx.x * blockDim.x + threadIdx.x;
    int wave = gtid >> 6;
    int lane = threadIdx.x & 63;
    int nwaves = (gridDim.x * blockDim.x) >> 6;
    for (int e = wave; e < E; e += nwaves) {
        int s = src[e], d = dst[e];
        float norm = dis[s] * dis[d];
        float2 v = ((const float2*)(XW + (size_t)s * 128))[lane];
        float* orow = out + (size_t)d * 128;
        atomicAdd(&orow[lane * 2 + 0], v.x * norm);
        atomicAdd(&orow[lane * 2 + 1], v.y * norm);
    }
}

__global__ void scatter64_kernel(const float* __restrict__ XW, const int* __restrict__ src,
                                 const int* __restrict__ dst, const float* __restrict__ dis,
                                 float* __restrict__ out, int E) {
    int gtid = blockIdx.x * blockDim.x + threadIdx.x;
    int wave = gtid >> 6;
    int lane = threadIdx.x & 63;
    int nwaves = (gridDim.x * blockDim.x) >> 6;
    for (int e = wave; e < E; e += nwaves) {
        int s = src[e], d = dst[e];
        float norm = dis[s] * dis[d];
        float v = XW[(size_t)s * 64 + lane];
        atomicAdd(&out[(size_t)d * 64 + lane], v * norm);
    }
}

// ================= launch =================

extern "C" void kernel_launch(void* const* d_in, const int* in_sizes, int n_in,
                              void* d_out, int out_size, void* d_ws, size_t ws_size,
                              hipStream_t stream) {
    const float* x     = (const float*)d_in[0];  // [n,180]
    const float* fc1_w = (const float*)d_in[1];  // [180,128]
    const float* fc1_b = (const float*)d_in[2];  // [128]
    const float* w1    = (const float*)d_in[3];  // [128,128]
    const float* b1    = (const float*)d_in[4];  // [128]
    const float* w2    = (const float*)d_in[5];  // [128,64]
    const float* b2    = (const float*)d_in[6];  // [64]
    const int*   edges = (const int*)d_in[7];    // [2,E] int32

    const int IN_DIM = 180, HID = 128, OUT_DIM = 64;
    const int n = in_sizes[0] / IN_DIM;          // 50000
    const int E = in_sizes[7] / 2;               // 800000
    const int* src = edges;
    const int* dst = edges + E;

    float* out = (float*)d_out;                  // [n,64]

    char* ws = (char*)d_ws;
    auto align = [](size_t v) { return (v + 255) & ~(size_t)255; };

    size_t off = 0;
    int*   deg       = (int*)(ws + off);  off += align((size_t)n * sizeof(int));
    float* dis       = (float*)(ws + off); off += align((size_t)n * sizeof(float));
    int*   row_start = (int*)(ws + off);  off += align((size_t)(n + 1) * sizeof(int));
    int*   cursor    = (int*)(ws + off);  off += align((size_t)n * sizeof(int));
    int*   csr       = (int*)(ws + off);  off += align((size_t)E * sizeof(int));
    float* bufA      = (float*)(ws + off); off += align((size_t)n * HID * sizeof(float));
    float* bufB      = (float*)(ws + off); off += align((size_t)n * HID * sizeof(float));
    const bool use_csr = (off <= ws_size);

    constexpr int TMG = 16, RG = 2;
    const int TM = TMG * RG;                      // 32 rows per block
    const int nblk256 = (n + 255) / 256;
    const int eblk256 = (E + 255) / 256;
    const int ggrid = (n + TM - 1) / TM;          // 1563

    // degree + normalization (shared by both paths)
    deg_init_kernel<<<nblk256, 256, 0, stream>>>(deg, n);
    deg_count_kernel<<<eblk256, 256, 0, stream>>>(dst, E, deg);
    dis_kernel<<<nblk256, 256, 0, stream>>>(deg, dis, n);

    if (use_csr) {
        // CSR build
        scan_kernel<<<1, 1024, 0, stream>>>(deg, row_start, cursor, n);
        csr_fill_kernel<<<eblk256, 256, 0, stream>>>(src, dst, E, cursor, csr);

        // H1 = relu(x @ fc1_w + fc1_b) -> bufA
        gemm_kernel<180, 128, TMG, RG, false, true, true, false>
            <<<ggrid, 128 * RG, TM * 180 * sizeof(float), stream>>>(
                x, fc1_w, fc1_b, nullptr, bufA, n);

        // y1 = dis * (H1 @ w1) -> bufB
        gemm_kernel<128, 128, TMG, RG, false, false, false, true>
            <<<ggrid, 128 * RG, TM * 128 * sizeof(float), stream>>>(
                bufA, w1, nullptr, dis, bufB, n);

        // H2 = relu(dis[d]*(y1[d] + sum y1[s]) + b1) -> bufA
        gather128_kernel<true><<<(n + 3) / 4, 256, 0, stream>>>(
            bufB, row_start, csr, dis, b1, bufA, n);

        // y2 = dis * (H2 @ w2) -> bufB
        gemm_kernel<128, 64, TMG, RG, false, false, false, true>
            <<<ggrid, 64 * RG, TM * 128 * sizeof(float), stream>>>(
                bufA, w2, nullptr, dis, bufB, n);

        // out = dis[d]*(y2[d] + sum y2[s]) + b2
        gather64_kernel<false><<<(n + 3) / 4, 256, 0, stream>>>(
            bufB, row_start, csr, dis, b2, out, n);
    } else {
        // fallback: atomic scatter path
        size_t o2 = 0;
        o2 += align((size_t)n * sizeof(int));     // deg
        o2 += align((size_t)n * sizeof(float));   // dis
        float* bA = (float*)(ws + o2); o2 += align((size_t)n * HID * sizeof(float));
        float* bB = (float*)(ws + o2);

        gemm_kernel<180, 128, TMG, RG, false, true, true, false>
            <<<ggrid, 128 * RG, TM * 180 * sizeof(float), stream>>>(
                x, fc1_w, fc1_b, nullptr, bA, n);
        gemm_kernel<128, 128, TMG, RG, false, false, false, false>
            <<<ggrid, 128 * RG, TM * 128 * sizeof(float), stream>>>(
                bA, w1, nullptr, nullptr, bB, n);
        self_init_kernel<128><<<((size_t)n * HID + 255) / 256, 256, 0, stream>>>(
            bB, dis, b1, bA, n);
        scatter128_kernel<<<8192, 256, 0, stream>>>(bB, src, dst, dis, bA, E);
        gemm_kernel<128, 64, TMG, RG, true, false, false, false>
            <<<ggrid, 64 * RG, TM * 128 * sizeof(float), stream>>>(
                bA, w2, nullptr, nullptr, bB, n);
        self_init_kernel<64><<<((size_t)n * OUT_DIM + 255) / 256, 256, 0, stream>>>(
            bB, dis, b2, out, n);
        scatter64_kernel<<<8192, 256, 0, stream>>>(bB, src, dst, dis, out, E);
    }
}

// Round 8
// 458.057 us; speedup vs baseline: 2.5482x; 1.1745x over previous
//
#include <hip/hip_runtime.h>
#include <math.h>

// ================= degree / normalization =================

__global__ void deg_init_kernel(int* __restrict__ deg, int n) {
    int i = blockIdx.x * blockDim.x + threadIdx.x;
    if (i < n) deg[i] = 1;  // self loop
}

__global__ void deg_count_kernel(const int* __restrict__ dst, int E, int* __restrict__ deg) {
    int i = blockIdx.x * blockDim.x + threadIdx.x;
    if (i < E) atomicAdd(&deg[dst[i]], 1);
}

__global__ void dis_kernel(const int* __restrict__ deg, float* __restrict__ dis, int n) {
    int i = blockIdx.x * blockDim.x + threadIdx.x;
    if (i < n) dis[i] = rsqrtf((float)deg[i]);
}

// ================= CSR build: 3-phase parallel exclusive scan =================
// indeg = deg-1; 1024 elements per block (256 threads x 4).

__global__ void scan_partial_kernel(const int* __restrict__ deg, int* __restrict__ bsum, int n) {
    __shared__ int sm[256];
    const int b = blockIdx.x, tid = threadIdx.x;
    const int base = b * 1024 + tid * 4;
    int s = 0;
#pragma unroll
    for (int j = 0; j < 4; ++j) {
        int i = base + j;
        if (i < n) s += deg[i] - 1;
    }
    sm[tid] = s;
    __syncthreads();
    for (int off = 128; off > 0; off >>= 1) {
        if (tid < off) sm[tid] += sm[tid + off];
        __syncthreads();
    }
    if (tid == 0) bsum[b] = sm[0];
}

// single block; nb <= 256 required (n <= 262144)
__global__ void scan_bsum_kernel(int* __restrict__ bsum, int nb) {
    __shared__ int sm[256];
    const int tid = threadIdx.x;
    int v = (tid < nb) ? bsum[tid] : 0;
    sm[tid] = v;
    __syncthreads();
    for (int off = 1; off < 256; off <<= 1) {
        int t = (tid >= off) ? sm[tid - off] : 0;
        __syncthreads();
        sm[tid] += t;
        __syncthreads();
    }
    if (tid < nb) bsum[tid] = sm[tid] - v;  // exclusive
}

__global__ void scan_fill_kernel(const int* __restrict__ deg, const int* __restrict__ bsum,
                                 int* __restrict__ row_start, int* __restrict__ cursor,
                                 int n, int E) {
    __shared__ int sm[256];
    const int b = blockIdx.x, tid = threadIdx.x;
    const int base = b * 1024 + tid * 4;
    int v[4];
    int s = 0;
#pragma unroll
    for (int j = 0; j < 4; ++j) {
        int i = base + j;
        v[j] = (i < n) ? (deg[i] - 1) : 0;
        s += v[j];
    }
    sm[tid] = s;
    __syncthreads();
    for (int off = 1; off < 256; off <<= 1) {
        int t = (tid >= off) ? sm[tid - off] : 0;
        __syncthreads();
        sm[tid] += t;
        __syncthreads();
    }
    int run = bsum[b] + sm[tid] - s;  // global exclusive prefix at this thread's first elem
#pragma unroll
    for (int j = 0; j < 4; ++j) {
        int i = base + j;
        if (i < n) {
            row_start[i] = run;
            cursor[i] = run;
            run += v[j];
        }
    }
    if (b == 0 && tid == 0) row_start[n] = E;  // sum(indeg) == E exactly
}

__global__ void csr_fill_kernel(const int* __restrict__ src, const int* __restrict__ dst,
                                int E, int* __restrict__ cursor, int* __restrict__ csr) {
    int e = blockIdx.x * blockDim.x + threadIdx.x;
    if (e < E) {
        int pos = atomicAdd(&cursor[dst[e]], 1);
        csr[pos] = src[e];
    }
}

// ================= fp32 GEMM, latency-tolerant (validated round 7) =================
// C[M,NT] = op_in(A[M,KT]) @ W[KT,NT] (+bias) (relu_out) (optionally * dis[row])

template<int KT, int NT, int TMG, int RG, bool RELU_IN, bool RELU_OUT, bool BIAS, bool DIS_SCALE>
__global__ __launch_bounds__(NT* RG) void gemm_kernel(
    const float* __restrict__ A, const float* __restrict__ W,
    const float* __restrict__ bias, const float* __restrict__ dis,
    float* __restrict__ C, int M) {
    constexpr int TM = TMG * RG;
    extern __shared__ float As[];  // TM*KT floats
    const int row0 = blockIdx.x * TM;
    const int tid  = threadIdx.x;
    const int col  = tid & (NT - 1);
    const int rg   = tid / NT;

    constexpr int TOTAL = TM * KT;
    for (int idx = tid; idx < TOTAL; idx += NT * RG) {
        int r = idx / KT;
        int k = idx - r * KT;
        int gr = row0 + r;
        float v = (gr < M) ? A[(size_t)gr * KT + k] : 0.0f;
        if (RELU_IN) v = fmaxf(v, 0.0f);
        As[idx] = v;
    }
    __syncthreads();

    float acc[TMG];
#pragma unroll
    for (int r = 0; r < TMG; ++r) acc[r] = 0.0f;

    const float* Ab = As + rg * TMG * KT;
    const float* Wc = W + col;

    auto ldW = [&](int k) {
        return make_float4(Wc[(size_t)(k + 0) * NT], Wc[(size_t)(k + 1) * NT],
                           Wc[(size_t)(k + 2) * NT], Wc[(size_t)(k + 3) * NT]);
    };
    auto step = [&](int k, float4 w) {
#pragma unroll
        for (int r = 0; r < TMG; ++r) {
            float4 a = *(const float4*)(Ab + r * KT + k);
            acc[r] += a.x * w.x + a.y * w.y + a.z * w.z + a.w * w.w;
        }
    };

    float4 wa = ldW(0), wb;
    int k = 0;
    while (true) {
        if (k + 4 < KT) wb = ldW(k + 4);
        step(k, wa);
        k += 4;
        if (k >= KT) break;
        if (k + 4 < KT) wa = ldW(k + 4);
        step(k, wb);
        k += 4;
        if (k >= KT) break;
    }

    float b = BIAS ? bias[col] : 0.0f;
#pragma unroll
    for (int r = 0; r < TMG; ++r) {
        int gr = row0 + rg * TMG + r;
        if (gr < M) {
            float v = acc[r];
            if (DIS_SCALE) v *= dis[gr];
            v += b;
            if (RELU_OUT) v = fmaxf(v, 0.0f);
            C[(size_t)gr * NT + col] = v;
        }
    }
}

// ================= CSR gather aggregation (validated round 5) =================
// out[d] = (maybe relu)( dis[d] * (y[d] + sum_{s in N(d)} y[s]) + bias )

template<bool RELU>
__global__ void gather128_kernel(const float* __restrict__ y, const int* __restrict__ row_start,
                                 const int* __restrict__ csr, const float* __restrict__ dis,
                                 const float* __restrict__ bias, float* __restrict__ out, int n) {
    int w = (blockIdx.x * blockDim.x + threadIdx.x) >> 6;
    if (w >= n) return;
    int lane = threadIdx.x & 63;

    float2 acc = ((const float2*)(y + (size_t)w * 128))[lane];  // self loop
    int p  = row_start[w];
    int pe = row_start[w + 1];
    for (; p + 1 < pe; p += 2) {
        int s0 = __builtin_amdgcn_readfirstlane(csr[p]);
        int s1 = __builtin_amdgcn_readfirstlane(csr[p + 1]);
        float2 v0 = ((const float2*)(y + (size_t)s0 * 128))[lane];
        float2 v1 = ((const float2*)(y + (size_t)s1 * 128))[lane];
        acc.x += v0.x + v1.x;
        acc.y += v0.y + v1.y;
    }
    if (p < pe) {
        int s0 = __builtin_amdgcn_readfirstlane(csr[p]);
        float2 v0 = ((const float2*)(y + (size_t)s0 * 128))[lane];
        acc.x += v0.x;
        acc.y += v0.y;
    }
    float dd = dis[w];
    float2 b = ((const float2*)bias)[lane];
    float ox = acc.x * dd + b.x;
    float oy = acc.y * dd + b.y;
    if (RELU) { ox = fmaxf(ox, 0.0f); oy = fmaxf(oy, 0.0f); }
    ((float2*)(out + (size_t)w * 128))[lane] = make_float2(ox, oy);
}

template<bool RELU>
__global__ void gather64_kernel(const float* __restrict__ y, const int* __restrict__ row_start,
                                const int* __restrict__ csr, const float* __restrict__ dis,
                                const float* __restrict__ bias, float* __restrict__ out, int n) {
    int w = (blockIdx.x * blockDim.x + threadIdx.x) >> 6;
    if (w >= n) return;
    int lane = threadIdx.x & 63;

    float acc = y[(size_t)w * 64 + lane];  // self loop
    int p  = row_start[w];
    int pe = row_start[w + 1];
    for (; p + 1 < pe; p += 2) {
        int s0 = __builtin_amdgcn_readfirstlane(csr[p]);
        int s1 = __builtin_amdgcn_readfirstlane(csr[p + 1]);
        float v0 = y[(size_t)s0 * 64 + lane];
        float v1 = y[(size_t)s1 * 64 + lane];
        acc += v0 + v1;
    }
    if (p < pe) {
        int s0 = __builtin_amdgcn_readfirstlane(csr[p]);
        acc += y[(size_t)s0 * 64 + lane];
    }
    float v = acc * dis[w] + bias[lane];
    if (RELU) v = fmaxf(v, 0.0f);
    out[(size_t)w * 64 + lane] = v;
}

// ================= launch =================

extern "C" void kernel_launch(void* const* d_in, const int* in_sizes, int n_in,
                              void* d_out, int out_size, void* d_ws, size_t ws_size,
                              hipStream_t stream) {
    const float* x     = (const float*)d_in[0];  // [n,180]
    const float* fc1_w = (const float*)d_in[1];  // [180,128]
    const float* fc1_b = (const float*)d_in[2];  // [128]
    const float* w1    = (const float*)d_in[3];  // [128,128]
    const float* b1    = (const float*)d_in[4];  // [128]
    const float* w2    = (const float*)d_in[5];  // [128,64]
    const float* b2    = (const float*)d_in[6];  // [64]
    const int*   edges = (const int*)d_in[7];    // [2,E] int32

    const int IN_DIM = 180, HID = 128, OUT_DIM = 64;
    const int n = in_sizes[0] / IN_DIM;          // 50000
    const int E = in_sizes[7] / 2;               // 800000
    const int* src = edges;
    const int* dst = edges + E;

    float* out = (float*)d_out;                  // [n,64]

    char* ws = (char*)d_ws;
    auto align = [](size_t v) { return (v + 255) & ~(size_t)255; };

    size_t off = 0;
    int*   deg       = (int*)(ws + off);  off += align((size_t)n * sizeof(int));
    float* dis       = (float*)(ws + off); off += align((size_t)n * sizeof(float));
    int*   row_start = (int*)(ws + off);  off += align((size_t)(n + 1) * sizeof(int));
    int*   cursor    = (int*)(ws + off);  off += align((size_t)n * sizeof(int));
    int*   bsum      = (int*)(ws + off);  off += align((size_t)256 * sizeof(int));
    int*   csr       = (int*)(ws + off);  off += align((size_t)E * sizeof(int));
    float* bufA      = (float*)(ws + off); off += align((size_t)n * HID * sizeof(float));
    float* bufB      = (float*)(ws + off); off += align((size_t)n * HID * sizeof(float));
    (void)ws_size;

    constexpr int TMG = 16, RG = 2;
    const int TM = TMG * RG;                      // 32 rows per block
    const int nblk256 = (n + 255) / 256;
    const int eblk256 = (E + 255) / 256;
    const int ggrid = (n + TM - 1) / TM;          // 1563
    const int scan_blocks = (n + 1023) / 1024;    // 49 (<=256 required)

    // degree + normalization
    deg_init_kernel<<<nblk256, 256, 0, stream>>>(deg, n);
    deg_count_kernel<<<eblk256, 256, 0, stream>>>(dst, E, deg);
    dis_kernel<<<nblk256, 256, 0, stream>>>(deg, dis, n);

    // CSR build (3-phase parallel scan, then fill)
    scan_partial_kernel<<<scan_blocks, 256, 0, stream>>>(deg, bsum, n);
    scan_bsum_kernel<<<1, 256, 0, stream>>>(bsum, scan_blocks);
    scan_fill_kernel<<<scan_blocks, 256, 0, stream>>>(deg, bsum, row_start, cursor, n, E);
    csr_fill_kernel<<<eblk256, 256, 0, stream>>>(src, dst, E, cursor, csr);

    // H1 = relu(x @ fc1_w + fc1_b) -> bufA
    gemm_kernel<180, 128, TMG, RG, false, true, true, false>
        <<<ggrid, 128 * RG, TM * 180 * sizeof(float), stream>>>(
            x, fc1_w, fc1_b, nullptr, bufA, n);

    // y1 = dis * (H1 @ w1) -> bufB
    gemm_kernel<128, 128, TMG, RG, false, false, false, true>
        <<<ggrid, 128 * RG, TM * 128 * sizeof(float), stream>>>(
            bufA, w1, nullptr, dis, bufB, n);

    // H2 = relu(dis[d]*(y1[d] + sum y1[s]) + b1) -> bufA
    gather128_kernel<true><<<(n + 3) / 4, 256, 0, stream>>>(
        bufB, row_start, csr, dis, b1, bufA, n);

    // y2 = dis * (H2 @ w2) -> bufB
    gemm_kernel<128, 64, TMG, RG, false, false, false, true>
        <<<ggrid, 64 * RG, TM * 128 * sizeof(float), stream>>>(
            bufA, w2, nullptr, dis, bufB, n);

    // out = dis[d]*(y2[d] + sum y2[s]) + b2
    gather64_kernel<false><<<(n + 3) / 4, 256, 0, stream>>>(
        bufB, row_start, csr, dis, b2, out, n);
}